// Round 11
// baseline (1154.539 us; speedup 1.0000x reference)
//
#include <hip/hip_runtime.h>
#include <cstdint>
#include <cstddef>

// ---------------------------------------------------------------------------
// TGN transformer attention layer, MI355X (gfx950).
//   k_prep  : pack k_q weights to f16; bq_eff (time-ones folded)
//   k_wcomp : Weff = [Wk;Wv] @ Wkv (f32) -> f16 fragment-packed; beff
//   CSR     : hist/scan/scatter over dst (scatter also emits dstc[pos])
//   k_q     : D rows: Q_ori -> Qh(f32), Kh_self, Vh_self (f16)
//   k_kv    : PERSISTENT CSR-ordered GEMM + att fusion.  BK=128 supers,
//             3 K-loop barriers; B VGPR-dbuf per 32-k sub-chunk; next tile's
//             csr/h/f/dt gathers issued under current tile's K-loop/epilogue
//             (T14 cross-tile prefetch).  Epilogue: Kh->LDS -> att;
//             Vh -> vhg[pos] sequential stores.
//   k_agg   : per-dst wave, STREAMS att+V rows with 4-deep register pipeline
//             + self term, weighted sum + relu + LN
// ---------------------------------------------------------------------------

typedef _Float16 f16_t;
typedef _Float16 f16x8 __attribute__((ext_vector_type(8)));
typedef _Float16 f16x4 __attribute__((ext_vector_type(4)));
typedef float    f32x4 __attribute__((ext_vector_type(4)));

#define MFMA16(a, b, c) __builtin_amdgcn_mfma_f32_16x16x32_f16(a, b, c, 0, 0, 0)

#define BARRIER()                                         \
  do {                                                    \
    asm volatile("s_waitcnt lgkmcnt(0)" ::: "memory");    \
    __builtin_amdgcn_sched_barrier(0);                    \
    __builtin_amdgcn_s_barrier();                         \
    __builtin_amdgcn_sched_barrier(0);                    \
  } while (0)

static __device__ __forceinline__ f32x4 zero4() {
  f32x4 v; v[0] = 0.f; v[1] = 0.f; v[2] = 0.f; v[3] = 0.f; return v;
}

// w_j = 10^(-9 j / 99)  ->  exp2(j * (-9*log2(10)/99))
#define TIMEW_LOG2 (-0.30199346317157837f)

// ---------------------------------------------------------------------------
__global__ void k_prep(const float* __restrict__ wq_lin,
                       const float* __restrict__ bq_lin,
                       const float* __restrict__ wq,
                       const float* __restrict__ wk,
                       const float* __restrict__ wv,
                       f16_t* __restrict__ wq1,
                       f16_t* __restrict__ w3,
                       float* __restrict__ bqe) {
  int i = blockIdx.x * 256 + threadIdx.x;
  if (i < 32768) {
    int o = i >> 7, k = i & 127;
    wq1[i] = (f16_t)wq_lin[o * 228 + k];
  } else if (i < 229376) {
    int j = i - 32768;
    int r = j >> 8, k = j & 255;
    const float* src = (r < 256) ? wq : ((r < 512) ? wk : wv);
    w3[j] = (f16_t)src[(r & 255) * 256 + k];
  } else if (i < 229632) {
    int o = i - 229376;
    float s = bq_lin[o];
    for (int j = 0; j < 100; ++j) s += wq_lin[o * 228 + 128 + j];
    bqe[o] = s;
  }
}

// ---------------------------------------------------------------------------
// k_wcomp: Weff[oc][c] = sum_m W23[oc][m] * Wkv[m][c]; packed:
//   idx = kc*16384 + g*4096 + oc*8 + j   (c = kc*32 + g*8 + j)
// ---------------------------------------------------------------------------
__global__ __launch_bounds__(384) void k_wcomp(
    const float* __restrict__ wkv_lin, const float* __restrict__ bkv,
    const float* __restrict__ wk, const float* __restrict__ bk,
    const float* __restrict__ wv, const float* __restrict__ bv,
    f16_t* __restrict__ weffp, float* __restrict__ beff) {
  __shared__ float wrow[256];
  const int oc = blockIdx.x;
  const float* src = (oc < 256) ? (wk + (size_t)oc * 256)
                                : (wv + (size_t)(oc - 256) * 256);
  const int t = threadIdx.x;
  if (t < 256) wrow[t] = src[t];
  __syncthreads();

  float acc = 0.f;
  if (t < 356) {
#pragma unroll 4
    for (int m = 0; m < 256; ++m) acc += wrow[m] * wkv_lin[(size_t)m * 356 + t];
  }
  int kc = t >> 5, g = (t >> 3) & 3, j = t & 7;
  weffp[(size_t)kc * 16384 + g * 4096 + oc * 8 + j] = (f16_t)acc;

  if (t == 0) {
    float b = (oc < 256) ? bk[oc] : bv[oc - 256];
    for (int m = 0; m < 256; ++m) b += wrow[m] * bkv[m];
    beff[oc] = b;
  }
}

// ---------------------------------------------------------------------------
// CSR build
// ---------------------------------------------------------------------------
__global__ void k_hist(const int* __restrict__ dst, int* __restrict__ rs, int E) {
  int e = blockIdx.x * 256 + threadIdx.x;
  if (e < E) atomicAdd(&rs[dst[e] + 1], 1);
}

__global__ void k_scan(int* __restrict__ rs, int* __restrict__ cur, int D) {
  __shared__ int sd[1024];
  __shared__ int srun;
  const int t = threadIdx.x;
  if (t == 0) srun = 0;
  __syncthreads();
  for (int base = 0; base < D; base += 1024) {
    const int i = base + t;
    int c = (i < D) ? rs[i + 1] : 0;
    sd[t] = c;
    __syncthreads();
    for (int off = 1; off < 1024; off <<= 1) {
      int v = (t >= off) ? sd[t - off] : 0;
      __syncthreads();
      sd[t] += v;
      __syncthreads();
    }
    const int incl = sd[t];
    const int run = srun;
    __syncthreads();
    if (i < D) {
      cur[i] = run + incl - c;
      rs[i + 1] = run + incl;
    }
    if (t == 1023) srun = run + sd[1023];
    __syncthreads();
  }
}

__global__ void k_scatter(const int* __restrict__ dst, int* __restrict__ cur,
                          int* __restrict__ csr, int* __restrict__ dstc, int E) {
  int e = blockIdx.x * 256 + threadIdx.x;
  if (e < E) {
    int d = dst[e];
    int pos = atomicAdd(&cur[d], 1);
    csr[pos] = e;
    dstc[pos] = d;
  }
}

__global__ void k_sentinel(float* __restrict__ o, int n) {
  int i = blockIdx.x * 256 + threadIdx.x;
  if (i < n) o[i] = 1e30f;
}

// ---------------------------------------------------------------------------
// k_q: 64 dst rows per block, 8 waves (small kernel, D=25k rows).
// ---------------------------------------------------------------------------
__global__ __launch_bounds__(512) void k_q(
    const float* __restrict__ h, const float* __restrict__ bqe,
    const float* __restrict__ bq, const float* __restrict__ bk,
    const float* __restrict__ bv, const f16_t* __restrict__ wq1,
    const f16_t* __restrict__ w3, float* __restrict__ qhd,
    f16_t* __restrict__ khs, f16_t* __restrict__ vhs, int D) {
  __shared__ f16_t sm[64 * 256];
  f16_t* xs = sm;
  f16_t* ks = sm;
  const int tid = threadIdx.x;
  const int dbase = blockIdx.x * 64;

  {
    const int r = tid >> 3, q = tid & 7;
    const int dd = min(dbase + r, D - 1);
    const int sw = r & 7;
    const float* p = h + (size_t)dd * 128 + q * 16;
#pragma unroll
    for (int u = 0; u < 2; ++u) {
      float4 v0 = *(const float4*)(p + u * 8);
      float4 v1 = *(const float4*)(p + u * 8 + 4);
      f16x8 w8;
      w8[0] = (f16_t)v0.x; w8[1] = (f16_t)v0.y; w8[2] = (f16_t)v0.z; w8[3] = (f16_t)v0.w;
      w8[4] = (f16_t)v1.x; w8[5] = (f16_t)v1.y; w8[6] = (f16_t)v1.z; w8[7] = (f16_t)v1.w;
      *(f16x8*)&xs[r * 128 + (((2 * q + u) ^ sw) << 3)] = w8;
    }
  }
  __syncthreads();

  const int lane = tid & 63;
  const int wv_ = tid >> 6;
  const int m16 = lane & 15;
  const int g = lane >> 4;

  f32x4 acc1[4][2];
#pragma unroll
  for (int mt = 0; mt < 4; ++mt)
#pragma unroll
    for (int nt = 0; nt < 2; ++nt) acc1[mt][nt] = zero4();

#pragma unroll
  for (int kt = 0; kt < 4; ++kt) {
    f16x8 a[4];
#pragma unroll
    for (int mt = 0; mt < 4; ++mt) {
      int row = mt * 16 + m16;
      a[mt] = *(const f16x8*)&xs[row * 128 + ((((kt << 2) + g) ^ (row & 7)) << 3)];
    }
#pragma unroll
    for (int nt = 0; nt < 2; ++nt) {
      int col = wv_ * 32 + nt * 16 + m16;
      f16x8 b = *(const f16x8*)&wq1[(size_t)col * 128 + (kt << 5) + (g << 3)];
#pragma unroll
      for (int mt = 0; mt < 4; ++mt) acc1[mt][nt] = MFMA16(a[mt], b, acc1[mt][nt]);
    }
  }
  __syncthreads();

#pragma unroll
  for (int nt = 0; nt < 2; ++nt) {
    int col = wv_ * 32 + nt * 16 + m16;
    float bias = bqe[col];
#pragma unroll
    for (int mt = 0; mt < 4; ++mt)
#pragma unroll
      for (int j = 0; j < 4; ++j) {
        int row = mt * 16 + (g << 2) + j;
        ks[row * 256 + ((((col >> 3) ^ (row & 7)) << 3)) + (col & 7)] =
            (f16_t)(acc1[mt][nt][j] + bias);
      }
  }
  __syncthreads();

#pragma unroll
  for (int p = 0; p < 3; ++p) {
    const f16_t* wsec = w3 + ((size_t)p << 16);
    const float* bsec = (p == 0) ? bq : ((p == 1) ? bk : bv);
    f32x4 acc[4][2];
#pragma unroll
    for (int mt = 0; mt < 4; ++mt)
#pragma unroll
      for (int nt = 0; nt < 2; ++nt) acc[mt][nt] = zero4();
#pragma unroll
    for (int kt = 0; kt < 8; ++kt) {
      f16x8 a[4];
#pragma unroll
      for (int mt = 0; mt < 4; ++mt) {
        int row = mt * 16 + m16;
        a[mt] = *(const f16x8*)&ks[row * 256 + ((((kt << 2) + g) ^ (row & 7)) << 3)];
      }
#pragma unroll
      for (int nt = 0; nt < 2; ++nt) {
        int col = wv_ * 32 + nt * 16 + m16;
        f16x8 b = *(const f16x8*)&wsec[(size_t)col * 256 + (kt << 5) + (g << 3)];
#pragma unroll
        for (int mt = 0; mt < 4; ++mt) acc[mt][nt] = MFMA16(a[mt], b, acc[mt][nt]);
      }
    }
#pragma unroll
    for (int nt = 0; nt < 2; ++nt) {
      int col = wv_ * 32 + nt * 16 + m16;
      float bias = bsec[col];
#pragma unroll
      for (int mt = 0; mt < 4; ++mt)
#pragma unroll
        for (int j = 0; j < 4; ++j) {
          int row = mt * 16 + (g << 2) + j;
          int dd = dbase + row;
          if (dd < D) {
            float val = acc[mt][nt][j] + bias;
            if (p == 0)
              qhd[(size_t)dd * 256 + col] = val;
            else if (p == 1)
              khs[(size_t)dd * 256 + col] = (f16_t)val;
            else
              vhs[(size_t)dd * 256 + col] = (f16_t)val;
          }
        }
    }
  }
}

// ---------------------------------------------------------------------------
// k_kv: persistent CSR-ordered GEMM + att fusion.
//   512 blocks (2/CU), grid-stride over tiles of 128 CSR rows.
//   1024 threads = 16 waves (wm 2 x wn 8, 64x64/wave).
//   Per tile: h->buf0 + f->buf1 staged up front; chunks 0-3 (h), stage time
//   into buf0 after BAR-B, chunks 4-7 (f), chunks 8-11 (time).  B VGPR-dbuf
//   per 32-k chunk from L2.  Next tile's csr issued post-BAR-A; its h/f/dt
//   gathers issued post-chunk-11 (hidden under epilogue).
// ---------------------------------------------------------------------------
__global__ __launch_bounds__(1024, 2) void k_kv(
    const float* __restrict__ h, const float* __restrict__ f,
    const float* __restrict__ dt, const f16_t* __restrict__ weffp,
    const float* __restrict__ beff, const int* __restrict__ csr,
    const int* __restrict__ dstc, const float* __restrict__ qhd,
    float* __restrict__ att, f16_t* __restrict__ vhg, int D, int E,
    int ntiles) {
  __shared__ __align__(16) unsigned char smem[81920];  // 2 x 40 KB A supers

  const int tid = threadIdx.x;
  const int row = tid >> 3, q = tid & 7;
  const int lane = tid & 63, wid = tid >> 6;
  const int wm = wid >> 3, wn = wid & 7;
  const int m16 = lane & 15, g = lane >> 4;

  auto stageA = [&](int buf, int sub, float4 v) {
    f16x4 w;
    w[0] = (f16_t)v.x; w[1] = (f16_t)v.y; w[2] = (f16_t)v.z; w[3] = (f16_t)v.w;
    *(f16x4*)(smem + buf * 40960 + sub * 10240 + row * 80 + q * 8) = w;
  };
  const f16_t* wb = weffp + (size_t)g * 4096 + ((size_t)(wn * 64 + m16) << 3);
  auto gldB = [&](int kc, f16x8* d) {
    const f16_t* pB = wb + (size_t)kc * 16384;
#pragma unroll
    for (int n = 0; n < 4; ++n) d[n] = *(const f16x8*)(pB + n * 128);
  };

  f32x4 acc[4][4];
  auto doChunk = [&](int kc, const f16x8* bbuf) {
    const unsigned char* Ac =
        smem + (((kc >> 2) == 1) ? 40960 : 0) + (kc & 3) * 10240;
#pragma unroll
    for (int mt = 0; mt < 4; ++mt) {
      f16x8 afr = *(const f16x8*)(Ac + (wm * 64 + mt * 16 + m16) * 80 + g * 16);
#pragma unroll
      for (int n = 0; n < 4; ++n) acc[mt][n] = MFMA16(afr, bbuf[n], acc[mt][n]);
    }
  };

  // current-tile staging registers (prefetched one tile ahead)
  float4 hv[4], fv[4];
  float dtv = 0.f;

  int t = blockIdx.x;
  if (t < ntiles) {
    int e = csr[min(t * 128 + row, E - 1)];
    dtv = dt[e];
    const float* hr = h + (size_t)(D + e) * 128 + q * 4;
    const float* fr = f + (size_t)e * 128 + q * 4;
#pragma unroll
    for (int s = 0; s < 4; ++s) hv[s] = *(const float4*)(hr + s * 32);
#pragma unroll
    for (int s = 0; s < 4; ++s) fv[s] = *(const float4*)(fr + s * 32);
  }

  for (; t < ntiles; t += gridDim.x) {
    const int pbase = t * 128;
#pragma unroll
    for (int mt = 0; mt < 4; ++mt)
#pragma unroll
      for (int n = 0; n < 4; ++n) acc[mt][n] = zero4();

    // stage h -> buf0, f -> buf1 (from prefetched registers)
#pragma unroll
    for (int s = 0; s < 4; ++s) stageA(0, s, hv[s]);
#pragma unroll
    for (int s = 0; s < 4; ++s) stageA(1, s, fv[s]);
    BARRIER();  // A: both supers staged

    // next tile's csr row-id (latency hidden under K-loop)
    const int tn = t + gridDim.x;
    int en = 0;
    if (tn < ntiles) en = csr[min(tn * 128 + row, E - 1)];

    f16x8 bb0[4], bb1[4];
    gldB(0, bb0);
    gldB(1, bb1); doChunk(0, bb0);
    gldB(2, bb0); doChunk(1, bb1);
    gldB(3, bb1); doChunk(2, bb0);
    gldB(4, bb0); doChunk(3, bb1);
    BARRIER();  // B: buf0 (h) free

    // stage time-super into buf0 (uses current tile's dtv)
#pragma unroll
    for (int s = 0; s < 4; ++s) {
      float4 a;
#pragma unroll
      for (int j = 0; j < 4; ++j) {
        int cc = s * 32 + q * 4 + j;
        ((float*)&a)[j] =
            (cc < 100) ? __cosf(dtv * exp2f(TIMEW_LOG2 * (float)cc)) : 0.f;
      }
      stageA(0, s, a);
    }
    gldB(5, bb1); doChunk(4, bb0);
    gldB(6, bb0); doChunk(5, bb1);
    gldB(7, bb1); doChunk(6, bb0);
    gldB(8, bb0); doChunk(7, bb1);
    BARRIER();  // C: buf0 (time) staged

    gldB(9, bb1);  doChunk(8, bb0);
    gldB(10, bb0); doChunk(9, bb1);
    gldB(11, bb1); doChunk(10, bb0);
    doChunk(11, bb1);

    // next tile's h/f/dt gathers (hidden under epilogue)
    if (tn < ntiles) {
      const float* hr = h + (size_t)(D + en) * 128 + q * 4;
      const float* fr = f + (size_t)en * 128 + q * 4;
#pragma unroll
      for (int s = 0; s < 4; ++s) hv[s] = *(const float4*)(hr + s * 32);
#pragma unroll
      for (int s = 0; s < 4; ++s) fv[s] = *(const float4*)(fr + s * 32);
      dtv = dt[en];
    }
    BARRIER();  // D: K done, both bufs dead

    // ---- epilogue: ep = [128][264] f16 (67584 B, fits in smem)
    f16_t* ep = (f16_t*)smem;

    // pass 0: Kh (cols 0..255) -> LDS
    if ((wn >> 2) == 0) {
#pragma unroll
      for (int n = 0; n < 4; ++n) {
        const int c256 = (wn & 3) * 64 + n * 16 + m16;
        const float bias = beff[c256];
#pragma unroll
        for (int mt = 0; mt < 4; ++mt)
#pragma unroll
          for (int j = 0; j < 4; ++j) {
            const int r2 = wm * 64 + mt * 16 + (g << 2) + j;
            ep[r2 * 264 + c256] = (f16_t)(acc[mt][n][j] + bias);
          }
      }
    }
    BARRIER();  // E

    // att: run-coherent Q gather (CSR order)
    {
      const int r2 = tid >> 3, hp = tid & 7;
      const int p2 = pbase + r2;
      if (p2 < E) {
        const int de = dstc[p2];
        const float* qp = qhd + (size_t)de * 256 + hp * 32;
        const f16_t* kp = ep + r2 * 264 + hp * 32;
        float s = 0.f;
#pragma unroll
        for (int jj = 0; jj < 32; jj += 4) {
          float4 qv = *(const float4*)(qp + jj);
          f16x4 kv = *(const f16x4*)(kp + jj);
          s += qv.x * (float)kv[0] + qv.y * (float)kv[1] +
               qv.z * (float)kv[2] + qv.w * (float)kv[3];
        }
        s = (s > 0.f) ? s : 0.2f * s;
        att[(size_t)p2 * 8 + hp] = __expf(s);
      }
    }
    BARRIER();  // F: Kh reads done before Vh staging overwrites ep

    // pass 1: Vh (cols 256..511) -> LDS
    if ((wn >> 2) == 1) {
#pragma unroll
      for (int n = 0; n < 4; ++n) {
        const int c256 = (wn & 3) * 64 + n * 16 + m16;
        const float bias = beff[256 + c256];
#pragma unroll
        for (int mt = 0; mt < 4; ++mt)
#pragma unroll
          for (int j = 0; j < 4; ++j) {
            const int r2 = wm * 64 + mt * 16 + (g << 2) + j;
            ep[r2 * 264 + c256] = (f16_t)(acc[mt][n][j] + bias);
          }
      }
    }
    BARRIER();  // G

    // Vh stores: CSR-position rows -> fully sequential, coalesced
#pragma unroll
    for (int sweep = 0; sweep < 4; ++sweep) {
      const int flat = sweep * 8192 + tid * 8;
      const int r2 = flat >> 8, cc = flat & 255;
      const int p2 = pbase + r2;
      if (p2 < E) {
        f16x8 v = *(const f16x8*)&ep[r2 * 264 + cc];
        *(f16x8*)&vhg[(size_t)p2 * 256 + cc] = v;
      }
    }
    BARRIER();  // H: ep reads done before next tile's loop-top staging
  }
}

// ---------------------------------------------------------------------------
// k_agg: one wave per dst node; att + V rows CSR-ordered -> streaming with
// a 4-deep register pipeline (two static 4-wide banks; no runtime indexing).
// ---------------------------------------------------------------------------
__global__ __launch_bounds__(256) void k_agg(
    const float* __restrict__ qhd, const f16_t* __restrict__ khs,
    const f16_t* __restrict__ vhs, const float* __restrict__ att,
    const f16_t* __restrict__ vhg, const int* __restrict__ rs,
    const float* __restrict__ lng, const float* __restrict__ lnb,
    float* __restrict__ out, int D) {
  const int lane = threadIdx.x & 63;
  const int d = blockIdx.x * 4 + (threadIdx.x >> 6);
  if (d >= D) return;
  const int c0 = lane * 4;
  const int hd = lane >> 3;

  // self-loop term (score from f32 Q and f16 K_self)
  float den, a0, a1, a2, a3;
  {
    float4 qv = *(const float4*)(qhd + (size_t)d * 256 + c0);
    f16x4 ku = *(const f16x4*)(khs + (size_t)d * 256 + c0);
    f16x4 vu = *(const f16x4*)(vhs + (size_t)d * 256 + c0);
    float s = qv.x * (float)ku[0] + qv.y * (float)ku[1] +
              qv.z * (float)ku[2] + qv.w * (float)ku[3];
    s += __shfl_xor(s, 1); s += __shfl_xor(s, 2); s += __shfl_xor(s, 4);
    s = (s > 0.f) ? s : 0.2f * s;
    float ee = __expf(s);
    den = ee;
    a0 = ee * (float)vu[0]; a1 = ee * (float)vu[1];
    a2 = ee * (float)vu[2]; a3 = ee * (float)vu[3];
  }

  const int beg = rs[d], end = rs[d + 1];
  float ea0 = 0.f, ea1 = 0.f, ea2 = 0.f, ea3 = 0.f;
  float eb0 = 0.f, eb1 = 0.f, eb2 = 0.f, eb3 = 0.f;
  f16x4 va0 = {}, va1 = {}, va2 = {}, va3 = {};
  f16x4 vb0 = {}, vb1 = {}, vb2 = {}, vb3 = {};

#define LDQ(i, ee, vv)                                          \
  if ((i) < end) {                                              \
    ee = att[(size_t)(i) * 8 + hd];                             \
    vv = *(const f16x4*)(vhg + (size_t)(i) * 256 + c0);         \
  }
#define ACC(ee, vv)                                             \
  do {                                                          \
    den += ee;                                                  \
    a0 = fmaf(ee, (float)vv[0], a0);                            \
    a1 = fmaf(ee, (float)vv[1], a1);                            \
    a2 = fmaf(ee, (float)vv[2], a2);                            \
    a3 = fmaf(ee, (float)vv[3], a3);                            \
  } while (0)

  LDQ(beg + 0, ea0, va0);
  LDQ(beg + 1, ea1, va1);
  LDQ(beg + 2, ea2, va2);
  LDQ(beg + 3, ea3, va3);
  for (int idx = beg; idx < end; idx += 4) {
    LDQ(idx + 4, eb0, vb0);
    LDQ(idx + 5, eb1, vb1);
    LDQ(idx + 6, eb2, vb2);
    LDQ(idx + 7, eb3, vb3);
    ACC(ea0, va0);
    if (idx + 1 < end) ACC(ea1, va1);
    if (idx + 2 < end) ACC(ea2, va2);
    if (idx + 3 < end) ACC(ea3, va3);
    ea0 = eb0; va0 = vb0;
    ea1 = eb1; va1 = vb1;
    ea2 = eb2; va2 = vb2;
    ea3 = eb3; va3 = vb3;
  }
#undef LDQ
#undef ACC

  float x0 = fmaxf(a0 / den, 0.f), x1 = fmaxf(a1 / den, 0.f);
  float x2 = fmaxf(a2 / den, 0.f), x3 = fmaxf(a3 / den, 0.f);

  float s1 = x0 + x1 + x2 + x3;
#pragma unroll
  for (int m = 1; m < 64; m <<= 1) s1 += __shfl_xor(s1, m);
  float mu = s1 * (1.f / 256.f);
  float d0 = x0 - mu, d1 = x1 - mu, d2 = x2 - mu, d3 = x3 - mu;
  float s2 = d0 * d0 + d1 * d1 + d2 * d2 + d3 * d3;
#pragma unroll
  for (int m = 1; m < 64; m <<= 1) s2 += __shfl_xor(s2, m);
  float rstd = rsqrtf(s2 * (1.f / 256.f) + 1e-5f);

  float4 gg = *(const float4*)(lng + c0);
  float4 bb = *(const float4*)(lnb + c0);
  float4 o;
  o.x = d0 * rstd * gg.x + bb.x;
  o.y = d1 * rstd * gg.y + bb.y;
  o.z = d2 * rstd * gg.z + bb.z;
  o.w = d3 * rstd * gg.w + bb.w;
  *(float4*)(out + (size_t)d * 256 + c0) = o;
}

// ---------------------------------------------------------------------------
extern "C" void kernel_launch(void* const* d_in, const int* in_sizes, int n_in,
                              void* d_out, int out_size, void* d_ws,
                              size_t ws_size, hipStream_t stream) {
  const float* h       = (const float*)d_in[0];
  const float* f       = (const float*)d_in[1];
  const float* dt      = (const float*)d_in[2];
  const float* wq_lin  = (const float*)d_in[3];
  const float* bq_lin  = (const float*)d_in[4];
  const float* wkv_lin = (const float*)d_in[5];
  const float* bkv_lin = (const float*)d_in[6];
  const float* wq      = (const float*)d_in[7];
  const float* bq      = (const float*)d_in[8];
  const float* wk      = (const float*)d_in[9];
  const float* bk      = (const float*)d_in[10];
  const float* wv      = (const float*)d_in[11];
  const float* bv      = (const float*)d_in[12];
  const float* lng     = (const float*)d_in[13];
  const float* lnb     = (const float*)d_in[14];
  const int*   dst     = (const int*)d_in[15];

  const int S = in_sizes[0] / 128;
  const int E = in_sizes[2];
  const int D = S - E;
  float* out = (float*)d_out;

  char* p = (char*)d_ws;
  size_t off = 0;
  auto take = [&](size_t bytes) -> char* {
    char* r = p + off;
    off += (bytes + 255) & ~(size_t)255;
    return r;
  };
  f16_t* wq1   = (f16_t*)take((size_t)32768 * 2);
  f16_t* w3    = (f16_t*)take((size_t)196608 * 2);
  float* bqe   = (float*)take((size_t)256 * 4);
  f16_t* weffp = (f16_t*)take((size_t)196608 * 2);
  float* beff  = (float*)take((size_t)512 * 4);
  float* qhd   = (float*)take((size_t)D * 256 * 4);
  f16_t* khs   = (f16_t*)take((size_t)D * 256 * 2);
  f16_t* vhs   = (f16_t*)take((size_t)D * 256 * 2);
  float* att   = (float*)take((size_t)E * 8 * 4);
  f16_t* vhg   = (f16_t*)take((size_t)E * 256 * 2);
  int*   rs    = (int*)  take((size_t)(D + 1) * 4);
  int*   cur   = (int*)  take((size_t)D * 4);
  int*   csr   = (int*)  take((size_t)E * 4);
  int*   dstc  = (int*)  take((size_t)E * 4);

  if (off > ws_size) {
    k_sentinel<<<(out_size + 255) / 256, 256, 0, stream>>>(out, out_size);
    return;
  }

  const int ntiles = (E + 127) / 128;

  hipMemsetAsync(rs, 0, (size_t)(D + 1) * 4, stream);
  k_prep<<<898, 256, 0, stream>>>(wq_lin, bq_lin, wq, wk, wv, wq1, w3, bqe);
  k_wcomp<<<512, 384, 0, stream>>>(wkv_lin, bkv_lin, wk, bk, wv, bv, weffp,
                                   beff);
  k_hist<<<(E + 255) / 256, 256, 0, stream>>>(dst, rs, E);
  k_scan<<<1, 1024, 0, stream>>>(rs, cur, D);
  k_scatter<<<(E + 255) / 256, 256, 0, stream>>>(dst, cur, csr, dstc, E);
  k_q<<<(D + 63) / 64, 512, 0, stream>>>(h, bqe, bq, bk, bv, wq1, w3, qhd, khs,
                                         vhs, D);
  k_kv<<<512, 1024, 0, stream>>>(h, f, dt, weffp, beff, csr, dstc, qhd, att,
                                 vhg, D, E, ntiles);
  k_agg<<<(D + 3) / 4, 256, 0, stream>>>(qhd, khs, vhs, att, vhg, rs, lng, lnb,
                                         out, D);
}

// Round 12
// 592.961 us; speedup vs baseline: 1.9471x; 1.9471x over previous
//
#include <hip/hip_runtime.h>
#include <cstdint>
#include <cstddef>

// ---------------------------------------------------------------------------
// TGN transformer attention layer, MI355X (gfx950).
//   k_prep  : pack k_q weights to f16; bq_eff (time-ones folded)
//   k_wcomp : Weff = [Wk;Wv] @ Wkv (f32) -> f16 fragment-packed; beff
//   CSR     : hist/scan/scatter over dst (scatter also emits dstc[pos])
//   k_q     : D rows: Q_ori -> Qh(f32), Kh_self, Vh_self (f16)
//   k_kv    : CSR-ordered GEMM + att fusion.  64-row tiles, 512 threads =
//             8 waves -> 2 blocks/CU (cross-block latency hiding).  BK=128
//             supers, 3 K-loop barriers; B VGPR-dbuf per 32-k sub-chunk.
//             Epilogue: Kh->LDS -> att[pos][h]; Vh -> vhg[pos] sequential.
//   k_agg   : per-dst wave, streams att+V rows with 4-deep register pipeline
//             + self term, weighted sum + relu + LN
// ---------------------------------------------------------------------------

typedef _Float16 f16_t;
typedef _Float16 f16x8 __attribute__((ext_vector_type(8)));
typedef _Float16 f16x4 __attribute__((ext_vector_type(4)));
typedef float    f32x4 __attribute__((ext_vector_type(4)));

#define MFMA16(a, b, c) __builtin_amdgcn_mfma_f32_16x16x32_f16(a, b, c, 0, 0, 0)

#define BARRIER()                                         \
  do {                                                    \
    asm volatile("s_waitcnt lgkmcnt(0)" ::: "memory");    \
    __builtin_amdgcn_sched_barrier(0);                    \
    __builtin_amdgcn_s_barrier();                         \
    __builtin_amdgcn_sched_barrier(0);                    \
  } while (0)

static __device__ __forceinline__ f32x4 zero4() {
  f32x4 v; v[0] = 0.f; v[1] = 0.f; v[2] = 0.f; v[3] = 0.f; return v;
}

// w_j = 10^(-9 j / 99)  ->  exp2(j * (-9*log2(10)/99))
#define TIMEW_LOG2 (-0.30199346317157837f)

// ---------------------------------------------------------------------------
__global__ void k_prep(const float* __restrict__ wq_lin,
                       const float* __restrict__ bq_lin,
                       const float* __restrict__ wq,
                       const float* __restrict__ wk,
                       const float* __restrict__ wv,
                       f16_t* __restrict__ wq1,
                       f16_t* __restrict__ w3,
                       float* __restrict__ bqe) {
  int i = blockIdx.x * 256 + threadIdx.x;
  if (i < 32768) {
    int o = i >> 7, k = i & 127;
    wq1[i] = (f16_t)wq_lin[o * 228 + k];
  } else if (i < 229376) {
    int j = i - 32768;
    int r = j >> 8, k = j & 255;
    const float* src = (r < 256) ? wq : ((r < 512) ? wk : wv);
    w3[j] = (f16_t)src[(r & 255) * 256 + k];
  } else if (i < 229632) {
    int o = i - 229376;
    float s = bq_lin[o];
    for (int j = 0; j < 100; ++j) s += wq_lin[o * 228 + 128 + j];
    bqe[o] = s;
  }
}

// ---------------------------------------------------------------------------
// k_wcomp: Weff[oc][c] = sum_m W23[oc][m] * Wkv[m][c]; packed:
//   idx = kc*16384 + g*4096 + oc*8 + j   (c = kc*32 + g*8 + j)
// ---------------------------------------------------------------------------
__global__ __launch_bounds__(384) void k_wcomp(
    const float* __restrict__ wkv_lin, const float* __restrict__ bkv,
    const float* __restrict__ wk, const float* __restrict__ bk,
    const float* __restrict__ wv, const float* __restrict__ bv,
    f16_t* __restrict__ weffp, float* __restrict__ beff) {
  __shared__ float wrow[256];
  const int oc = blockIdx.x;
  const float* src = (oc < 256) ? (wk + (size_t)oc * 256)
                                : (wv + (size_t)(oc - 256) * 256);
  const int t = threadIdx.x;
  if (t < 256) wrow[t] = src[t];
  __syncthreads();

  float acc = 0.f;
  if (t < 356) {
#pragma unroll 4
    for (int m = 0; m < 256; ++m) acc += wrow[m] * wkv_lin[(size_t)m * 356 + t];
  }
  int kc = t >> 5, g = (t >> 3) & 3, j = t & 7;
  weffp[(size_t)kc * 16384 + g * 4096 + oc * 8 + j] = (f16_t)acc;

  if (t == 0) {
    float b = (oc < 256) ? bk[oc] : bv[oc - 256];
    for (int m = 0; m < 256; ++m) b += wrow[m] * bkv[m];
    beff[oc] = b;
  }
}

// ---------------------------------------------------------------------------
// CSR build
// ---------------------------------------------------------------------------
__global__ void k_hist(const int* __restrict__ dst, int* __restrict__ rs, int E) {
  int e = blockIdx.x * 256 + threadIdx.x;
  if (e < E) atomicAdd(&rs[dst[e] + 1], 1);
}

__global__ void k_scan(int* __restrict__ rs, int* __restrict__ cur, int D) {
  __shared__ int sd[1024];
  __shared__ int srun;
  const int t = threadIdx.x;
  if (t == 0) srun = 0;
  __syncthreads();
  for (int base = 0; base < D; base += 1024) {
    const int i = base + t;
    int c = (i < D) ? rs[i + 1] : 0;
    sd[t] = c;
    __syncthreads();
    for (int off = 1; off < 1024; off <<= 1) {
      int v = (t >= off) ? sd[t - off] : 0;
      __syncthreads();
      sd[t] += v;
      __syncthreads();
    }
    const int incl = sd[t];
    const int run = srun;
    __syncthreads();
    if (i < D) {
      cur[i] = run + incl - c;
      rs[i + 1] = run + incl;
    }
    if (t == 1023) srun = run + sd[1023];
    __syncthreads();
  }
}

__global__ void k_scatter(const int* __restrict__ dst, int* __restrict__ cur,
                          int* __restrict__ csr, int* __restrict__ dstc, int E) {
  int e = blockIdx.x * 256 + threadIdx.x;
  if (e < E) {
    int d = dst[e];
    int pos = atomicAdd(&cur[d], 1);
    csr[pos] = e;
    dstc[pos] = d;
  }
}

__global__ void k_sentinel(float* __restrict__ o, int n) {
  int i = blockIdx.x * 256 + threadIdx.x;
  if (i < n) o[i] = 1e30f;
}

// ---------------------------------------------------------------------------
// k_q: 64 dst rows per block, 8 waves (small kernel, D=25k rows).
// ---------------------------------------------------------------------------
__global__ __launch_bounds__(512) void k_q(
    const float* __restrict__ h, const float* __restrict__ bqe,
    const float* __restrict__ bq, const float* __restrict__ bk,
    const float* __restrict__ bv, const f16_t* __restrict__ wq1,
    const f16_t* __restrict__ w3, float* __restrict__ qhd,
    f16_t* __restrict__ khs, f16_t* __restrict__ vhs, int D) {
  __shared__ f16_t sm[64 * 256];
  f16_t* xs = sm;
  f16_t* ks = sm;
  const int tid = threadIdx.x;
  const int dbase = blockIdx.x * 64;

  {
    const int r = tid >> 3, q = tid & 7;
    const int dd = min(dbase + r, D - 1);
    const int sw = r & 7;
    const float* p = h + (size_t)dd * 128 + q * 16;
#pragma unroll
    for (int u = 0; u < 2; ++u) {
      float4 v0 = *(const float4*)(p + u * 8);
      float4 v1 = *(const float4*)(p + u * 8 + 4);
      f16x8 w8;
      w8[0] = (f16_t)v0.x; w8[1] = (f16_t)v0.y; w8[2] = (f16_t)v0.z; w8[3] = (f16_t)v0.w;
      w8[4] = (f16_t)v1.x; w8[5] = (f16_t)v1.y; w8[6] = (f16_t)v1.z; w8[7] = (f16_t)v1.w;
      *(f16x8*)&xs[r * 128 + (((2 * q + u) ^ sw) << 3)] = w8;
    }
  }
  __syncthreads();

  const int lane = tid & 63;
  const int wv_ = tid >> 6;
  const int m16 = lane & 15;
  const int g = lane >> 4;

  f32x4 acc1[4][2];
#pragma unroll
  for (int mt = 0; mt < 4; ++mt)
#pragma unroll
    for (int nt = 0; nt < 2; ++nt) acc1[mt][nt] = zero4();

#pragma unroll
  for (int kt = 0; kt < 4; ++kt) {
    f16x8 a[4];
#pragma unroll
    for (int mt = 0; mt < 4; ++mt) {
      int row = mt * 16 + m16;
      a[mt] = *(const f16x8*)&xs[row * 128 + ((((kt << 2) + g) ^ (row & 7)) << 3)];
    }
#pragma unroll
    for (int nt = 0; nt < 2; ++nt) {
      int col = wv_ * 32 + nt * 16 + m16;
      f16x8 b = *(const f16x8*)&wq1[(size_t)col * 128 + (kt << 5) + (g << 3)];
#pragma unroll
      for (int mt = 0; mt < 4; ++mt) acc1[mt][nt] = MFMA16(a[mt], b, acc1[mt][nt]);
    }
  }
  __syncthreads();

#pragma unroll
  for (int nt = 0; nt < 2; ++nt) {
    int col = wv_ * 32 + nt * 16 + m16;
    float bias = bqe[col];
#pragma unroll
    for (int mt = 0; mt < 4; ++mt)
#pragma unroll
      for (int j = 0; j < 4; ++j) {
        int row = mt * 16 + (g << 2) + j;
        ks[row * 256 + ((((col >> 3) ^ (row & 7)) << 3)) + (col & 7)] =
            (f16_t)(acc1[mt][nt][j] + bias);
      }
  }
  __syncthreads();

#pragma unroll
  for (int p = 0; p < 3; ++p) {
    const f16_t* wsec = w3 + ((size_t)p << 16);
    const float* bsec = (p == 0) ? bq : ((p == 1) ? bk : bv);
    f32x4 acc[4][2];
#pragma unroll
    for (int mt = 0; mt < 4; ++mt)
#pragma unroll
      for (int nt = 0; nt < 2; ++nt) acc[mt][nt] = zero4();
#pragma unroll
    for (int kt = 0; kt < 8; ++kt) {
      f16x8 a[4];
#pragma unroll
      for (int mt = 0; mt < 4; ++mt) {
        int row = mt * 16 + m16;
        a[mt] = *(const f16x8*)&ks[row * 256 + ((((kt << 2) + g) ^ (row & 7)) << 3)];
      }
#pragma unroll
      for (int nt = 0; nt < 2; ++nt) {
        int col = wv_ * 32 + nt * 16 + m16;
        f16x8 b = *(const f16x8*)&wsec[(size_t)col * 256 + (kt << 5) + (g << 3)];
#pragma unroll
        for (int mt = 0; mt < 4; ++mt) acc[mt][nt] = MFMA16(a[mt], b, acc[mt][nt]);
      }
    }
#pragma unroll
    for (int nt = 0; nt < 2; ++nt) {
      int col = wv_ * 32 + nt * 16 + m16;
      float bias = bsec[col];
#pragma unroll
      for (int mt = 0; mt < 4; ++mt)
#pragma unroll
        for (int j = 0; j < 4; ++j) {
          int row = mt * 16 + (g << 2) + j;
          int dd = dbase + row;
          if (dd < D) {
            float val = acc[mt][nt][j] + bias;
            if (p == 0)
              qhd[(size_t)dd * 256 + col] = val;
            else if (p == 1)
              khs[(size_t)dd * 256 + col] = (f16_t)val;
            else
              vhs[(size_t)dd * 256 + col] = (f16_t)val;
          }
        }
    }
  }
}

// ---------------------------------------------------------------------------
// k_kv: CSR-ordered GEMM + att fusion, 64-row tiles.
//   512 threads = 8 waves (wn 0..7, wave-tile 64x64, acc 4x4).
//   LDS: 2 x 20 KB A super-buffers (stride-80B rows); epilogue ep [64][264]
//   (33.8 KB) aliases them.  2 blocks/CU -> cross-block latency hiding.
//   K supers: h -> buf0, f -> buf1 staged up front; time -> buf0 after BAR-B.
//   B (weffp, L2) VGPR-dbuf per 32-k sub-chunk.
// ---------------------------------------------------------------------------
__global__ __launch_bounds__(512, 4) void k_kv(
    const float* __restrict__ h, const float* __restrict__ f,
    const float* __restrict__ dt, const f16_t* __restrict__ weffp,
    const float* __restrict__ beff, const int* __restrict__ csr,
    const int* __restrict__ dstc, const float* __restrict__ qhd,
    float* __restrict__ att, f16_t* __restrict__ vhg, int D, int E) {
  __shared__ __align__(16) unsigned char smem[40960];  // 2 x 20 KB A supers

  const int tid = threadIdx.x;
  const int pbase = blockIdx.x * 64;
  const int row = tid >> 3, q = tid & 7;     // 64 rows x 8 col-octets
  const int lane = tid & 63, wn = tid >> 6;  // 8 waves = 8 col groups
  const int m16 = lane & 15, g = lane >> 4;

  const int pclamp = min(pbase + row, E - 1);
  const int ec = csr[pclamp];
  const float dtv = dt[ec];
  const float* hrow = h + (size_t)(D + ec) * 128 + q * 4;
  const float* frow = f + (size_t)ec * 128 + q * 4;

  auto stageA = [&](int buf, int sub, float4 v) {
    f16x4 w;
    w[0] = (f16_t)v.x; w[1] = (f16_t)v.y; w[2] = (f16_t)v.z; w[3] = (f16_t)v.w;
    *(f16x4*)(smem + buf * 20480 + sub * 5120 + row * 80 + q * 8) = w;
  };
  const f16_t* wb = weffp + (size_t)g * 4096 + ((size_t)(wn * 64 + m16) << 3);
  auto gldB = [&](int kc, f16x8* d) {
    const f16_t* pB = wb + (size_t)kc * 16384;
#pragma unroll
    for (int n = 0; n < 4; ++n) d[n] = *(const f16x8*)(pB + n * 128);
  };

  f32x4 acc[4][4];
#pragma unroll
  for (int mt = 0; mt < 4; ++mt)
#pragma unroll
    for (int n = 0; n < 4; ++n) acc[mt][n] = zero4();

  auto doChunk = [&](int kc, const f16x8* bbuf) {
    const unsigned char* Ac =
        smem + (((kc >> 2) == 1) ? 20480 : 0) + (kc & 3) * 5120;
#pragma unroll
    for (int mt = 0; mt < 4; ++mt) {
      f16x8 afr = *(const f16x8*)(Ac + (mt * 16 + m16) * 80 + g * 16);
#pragma unroll
      for (int n = 0; n < 4; ++n) acc[mt][n] = MFMA16(afr, bbuf[n], acc[mt][n]);
    }
  };

  // load h-super + f-super (gathered 512B rows); stage h->buf0, f->buf1
  float4 hv[4], fv[4];
#pragma unroll
  for (int s = 0; s < 4; ++s) hv[s] = *(const float4*)(hrow + s * 32);
#pragma unroll
  for (int s = 0; s < 4; ++s) fv[s] = *(const float4*)(frow + s * 32);
#pragma unroll
  for (int s = 0; s < 4; ++s) stageA(0, s, hv[s]);
#pragma unroll
  for (int s = 0; s < 4; ++s) stageA(1, s, fv[s]);
  BARRIER();  // A: h (buf0) + f (buf1) staged

  f16x8 bb0[4], bb1[4];
  gldB(0, bb0);
  gldB(1, bb1); doChunk(0, bb0);
  gldB(2, bb0); doChunk(1, bb1);
  gldB(3, bb1); doChunk(2, bb0);
  gldB(4, bb0); doChunk(3, bb1);
  BARRIER();  // B: buf0 (h) consumed, free

  // stage time-super into buf0 (consumed after barrier C)
#pragma unroll
  for (int s = 0; s < 4; ++s) {
    float4 a;
#pragma unroll
    for (int j = 0; j < 4; ++j) {
      int cc = s * 32 + q * 4 + j;
      ((float*)&a)[j] =
          (cc < 100) ? __cosf(dtv * exp2f(TIMEW_LOG2 * (float)cc)) : 0.f;
    }
    stageA(0, s, a);
  }
  gldB(5, bb1); doChunk(4, bb0);
  gldB(6, bb0); doChunk(5, bb1);
  gldB(7, bb1); doChunk(6, bb0);
  gldB(8, bb0); doChunk(7, bb1);
  BARRIER();  // C: buf0 (time) ready

  gldB(9, bb1);  doChunk(8, bb0);
  gldB(10, bb0); doChunk(9, bb1);
  gldB(11, bb1); doChunk(10, bb0);
  doChunk(11, bb1);
  BARRIER();  // D: K done, both bufs dead

  // ---- epilogue: ep = [64][264] f16 (33792 B, aliases A buffers)
  f16_t* ep = (f16_t*)smem;

  // pass 0: Kh (cols 0..255) -> LDS (waves 0..3)
  if (wn < 4) {
#pragma unroll
    for (int n = 0; n < 4; ++n) {
      const int c256 = wn * 64 + n * 16 + m16;
      const float bias = beff[c256];
#pragma unroll
      for (int mt = 0; mt < 4; ++mt)
#pragma unroll
        for (int j = 0; j < 4; ++j) {
          const int r2 = mt * 16 + (g << 2) + j;
          ep[r2 * 264 + c256] = (f16_t)(acc[mt][n][j] + bias);
        }
    }
  }
  BARRIER();  // E

  // att: run-coherent Q gather (CSR order -> consecutive rows share dst)
  {
    const int r2 = tid >> 3, hp = tid & 7;
    const int p2 = pbase + r2;
    if (p2 < E) {
      const int de = dstc[p2];
      const float* qp = qhd + (size_t)de * 256 + hp * 32;
      const f16_t* kp = ep + r2 * 264 + hp * 32;
      float s = 0.f;
#pragma unroll
      for (int jj = 0; jj < 32; jj += 4) {
        float4 qv = *(const float4*)(qp + jj);
        f16x4 kv = *(const f16x4*)(kp + jj);
        s += qv.x * (float)kv[0] + qv.y * (float)kv[1] +
             qv.z * (float)kv[2] + qv.w * (float)kv[3];
      }
      s = (s > 0.f) ? s : 0.2f * s;
      att[(size_t)p2 * 8 + hp] = __expf(s);
    }
  }
  BARRIER();  // F: Kh reads done before Vh staging overwrites ep

  // pass 1: Vh (cols 256..511) -> LDS (waves 4..7)
  if (wn >= 4) {
#pragma unroll
    for (int n = 0; n < 4; ++n) {
      const int c256 = (wn - 4) * 64 + n * 16 + m16;
      const float bias = beff[256 + c256];
#pragma unroll
      for (int mt = 0; mt < 4; ++mt)
#pragma unroll
        for (int j = 0; j < 4; ++j) {
          const int r2 = mt * 16 + (g << 2) + j;
          ep[r2 * 264 + c256] = (f16_t)(acc[mt][n][j] + bias);
        }
    }
  }
  BARRIER();  // G

  // Vh stores: CSR-position rows -> fully sequential, coalesced
#pragma unroll
  for (int sweep = 0; sweep < 4; ++sweep) {
    const int flat = sweep * 4096 + tid * 8;
    const int r2 = flat >> 8, cc = flat & 255;
    const int p2 = pbase + r2;
    if (p2 < E) {
      f16x8 v = *(const f16x8*)&ep[r2 * 264 + cc];
      *(f16x8*)&vhg[(size_t)p2 * 256 + cc] = v;
    }
  }
}

// ---------------------------------------------------------------------------
// k_agg: one wave per dst node; att + V rows CSR-ordered -> streaming with
// a 4-deep register pipeline (two static 4-wide banks; no runtime indexing).
// ---------------------------------------------------------------------------
__global__ __launch_bounds__(256) void k_agg(
    const float* __restrict__ qhd, const f16_t* __restrict__ khs,
    const f16_t* __restrict__ vhs, const float* __restrict__ att,
    const f16_t* __restrict__ vhg, const int* __restrict__ rs,
    const float* __restrict__ lng, const float* __restrict__ lnb,
    float* __restrict__ out, int D) {
  const int lane = threadIdx.x & 63;
  const int d = blockIdx.x * 4 + (threadIdx.x >> 6);
  if (d >= D) return;
  const int c0 = lane * 4;
  const int hd = lane >> 3;

  // self-loop term (score from f32 Q and f16 K_self)
  float den, a0, a1, a2, a3;
  {
    float4 qv = *(const float4*)(qhd + (size_t)d * 256 + c0);
    f16x4 ku = *(const f16x4*)(khs + (size_t)d * 256 + c0);
    f16x4 vu = *(const f16x4*)(vhs + (size_t)d * 256 + c0);
    float s = qv.x * (float)ku[0] + qv.y * (float)ku[1] +
              qv.z * (float)ku[2] + qv.w * (float)ku[3];
    s += __shfl_xor(s, 1); s += __shfl_xor(s, 2); s += __shfl_xor(s, 4);
    s = (s > 0.f) ? s : 0.2f * s;
    float ee = __expf(s);
    den = ee;
    a0 = ee * (float)vu[0]; a1 = ee * (float)vu[1];
    a2 = ee * (float)vu[2]; a3 = ee * (float)vu[3];
  }

  const int beg = rs[d], end = rs[d + 1];
  float ea0 = 0.f, ea1 = 0.f, ea2 = 0.f, ea3 = 0.f;
  float eb0 = 0.f, eb1 = 0.f, eb2 = 0.f, eb3 = 0.f;
  f16x4 va0 = {}, va1 = {}, va2 = {}, va3 = {};
  f16x4 vb0 = {}, vb1 = {}, vb2 = {}, vb3 = {};

#define LDQ(i, ee, vv)                                          \
  if ((i) < end) {                                              \
    ee = att[(size_t)(i) * 8 + hd];                             \
    vv = *(const f16x4*)(vhg + (size_t)(i) * 256 + c0);         \
  }
#define ACC(ee, vv)                                             \
  do {                                                          \
    den += ee;                                                  \
    a0 = fmaf(ee, (float)vv[0], a0);                            \
    a1 = fmaf(ee, (float)vv[1], a1);                            \
    a2 = fmaf(ee, (float)vv[2], a2);                            \
    a3 = fmaf(ee, (float)vv[3], a3);                            \
  } while (0)

  LDQ(beg + 0, ea0, va0);
  LDQ(beg + 1, ea1, va1);
  LDQ(beg + 2, ea2, va2);
  LDQ(beg + 3, ea3, va3);
  for (int idx = beg; idx < end; idx += 4) {
    LDQ(idx + 4, eb0, vb0);
    LDQ(idx + 5, eb1, vb1);
    LDQ(idx + 6, eb2, vb2);
    LDQ(idx + 7, eb3, vb3);
    ACC(ea0, va0);
    if (idx + 1 < end) ACC(ea1, va1);
    if (idx + 2 < end) ACC(ea2, va2);
    if (idx + 3 < end) ACC(ea3, va3);
    ea0 = eb0; va0 = vb0;
    ea1 = eb1; va1 = vb1;
    ea2 = eb2; va2 = vb2;
    ea3 = eb3; va3 = vb3;
  }
#undef LDQ
#undef ACC

  float x0 = fmaxf(a0 / den, 0.f), x1 = fmaxf(a1 / den, 0.f);
  float x2 = fmaxf(a2 / den, 0.f), x3 = fmaxf(a3 / den, 0.f);

  float s1 = x0 + x1 + x2 + x3;
#pragma unroll
  for (int m = 1; m < 64; m <<= 1) s1 += __shfl_xor(s1, m);
  float mu = s1 * (1.f / 256.f);
  float d0 = x0 - mu, d1 = x1 - mu, d2 = x2 - mu, d3 = x3 - mu;
  float s2 = d0 * d0 + d1 * d1 + d2 * d2 + d3 * d3;
#pragma unroll
  for (int m = 1; m < 64; m <<= 1) s2 += __shfl_xor(s2, m);
  float rstd = rsqrtf(s2 * (1.f / 256.f) + 1e-5f);

  float4 gg = *(const float4*)(lng + c0);
  float4 bb = *(const float4*)(lnb + c0);
  float4 o;
  o.x = d0 * rstd * gg.x + bb.x;
  o.y = d1 * rstd * gg.y + bb.y;
  o.z = d2 * rstd * gg.z + bb.z;
  o.w = d3 * rstd * gg.w + bb.w;
  *(float4*)(out + (size_t)d * 256 + c0) = o;
}

// ---------------------------------------------------------------------------
extern "C" void kernel_launch(void* const* d_in, const int* in_sizes, int n_in,
                              void* d_out, int out_size, void* d_ws,
                              size_t ws_size, hipStream_t stream) {
  const float* h       = (const float*)d_in[0];
  const float* f       = (const float*)d_in[1];
  const float* dt      = (const float*)d_in[2];
  const float* wq_lin  = (const float*)d_in[3];
  const float* bq_lin  = (const float*)d_in[4];
  const float* wkv_lin = (const float*)d_in[5];
  const float* bkv_lin = (const float*)d_in[6];
  const float* wq      = (const float*)d_in[7];
  const float* bq      = (const float*)d_in[8];
  const float* wk      = (const float*)d_in[9];
  const float* bk      = (const float*)d_in[10];
  const float* wv      = (const float*)d_in[11];
  const float* bv      = (const float*)d_in[12];
  const float* lng     = (const float*)d_in[13];
  const float* lnb     = (const float*)d_in[14];
  const int*   dst     = (const int*)d_in[15];

  const int S = in_sizes[0] / 128;
  const int E = in_sizes[2];
  const int D = S - E;
  float* out = (float*)d_out;

  char* p = (char*)d_ws;
  size_t off = 0;
  auto take = [&](size_t bytes) -> char* {
    char* r = p + off;
    off += (bytes + 255) & ~(size_t)255;
    return r;
  };
  f16_t* wq1   = (f16_t*)take((size_t)32768 * 2);
  f16_t* w3    = (f16_t*)take((size_t)196608 * 2);
  float* bqe   = (float*)take((size_t)256 * 4);
  f16_t* weffp = (f16_t*)take((size_t)196608 * 2);
  float* beff  = (float*)take((size_t)512 * 4);
  float* qhd   = (float*)take((size_t)D * 256 * 4);
  f16_t* khs   = (f16_t*)take((size_t)D * 256 * 2);
  f16_t* vhs   = (f16_t*)take((size_t)D * 256 * 2);
  float* att   = (float*)take((size_t)E * 8 * 4);
  f16_t* vhg   = (f16_t*)take((size_t)E * 256 * 2);
  int*   rs    = (int*)  take((size_t)(D + 1) * 4);
  int*   cur   = (int*)  take((size_t)D * 4);
  int*   csr   = (int*)  take((size_t)E * 4);
  int*   dstc  = (int*)  take((size_t)E * 4);

  if (off > ws_size) {
    k_sentinel<<<(out_size + 255) / 256, 256, 0, stream>>>(out, out_size);
    return;
  }

  hipMemsetAsync(rs, 0, (size_t)(D + 1) * 4, stream);
  k_prep<<<898, 256, 0, stream>>>(wq_lin, bq_lin, wq, wk, wv, wq1, w3, bqe);
  k_wcomp<<<512, 384, 0, stream>>>(wkv_lin, bkv_lin, wk, bk, wv, bv, weffp,
                                   beff);
  k_hist<<<(E + 255) / 256, 256, 0, stream>>>(dst, rs, E);
  k_scan<<<1, 1024, 0, stream>>>(rs, cur, D);
  k_scatter<<<(E + 255) / 256, 256, 0, stream>>>(dst, cur, csr, dstc, E);
  k_q<<<(D + 63) / 64, 512, 0, stream>>>(h, bqe, bq, bk, bv, wq1, w3, qhd, khs,
                                         vhs, D);
  k_kv<<<(E + 63) / 64, 512, 0, stream>>>(h, f, dt, weffp, beff, csr, dstc,
                                          qhd, att, vhg, D, E);
  k_agg<<<(D + 3) / 4, 256, 0, stream>>>(qhd, khs, vhs, att, vhg, rs, lng, lnb,
                                         out, D);
}